// Round 1
// baseline (869.740 us; speedup 1.0000x reference)
//
#include <hip/hip_runtime.h>
#include <hip/hip_bf16.h>
#include <math.h>

#define GAMMA 0.1f

// ---------------------------------------------------------------------------
// Kernel A: fused  xW = x@W,  s = sigmoid(x@sc+sb),  Dk = x@dkw+dkb
// Block = 256 threads, handles BN=16 nodes. x rows staged in LDS.
// Each thread owns one output column h and accumulates NP node outputs,
// reading each W row once per block (W traffic amortized 16x).
// ---------------------------------------------------------------------------
template <int H>
__global__ __launch_bounds__(256) void fused_linear(
    const float* __restrict__ x, const float* __restrict__ W,
    const float* __restrict__ sc, const float* __restrict__ sb,
    const float* __restrict__ dkw, const float* __restrict__ dkb,
    float* __restrict__ xW, float* __restrict__ s, float* __restrict__ Dk,
    int N, int F) {
  constexpr int BN = 16;                 // nodes per block
  extern __shared__ float xs[];          // [BN][F]
  const int node0 = blockIdx.x * BN;
  const int t = threadIdx.x;

  // stage x rows (coalesced)
  const int total = BN * F;
  for (int i = t; i < total; i += 256) {
    int n = i / F;
    int f = i - n * F;
    int gn = node0 + n;
    xs[i] = (gn < N) ? x[(size_t)gn * F + f] : 0.f;
  }
  __syncthreads();

  constexpr int NSLOT = 256 / H;         // node slots processed concurrently
  constexpr int NP = BN / NSLOT;         // accumulators per thread
  const int h = t % H;
  const int nl = t / H;

  float acc[NP];
#pragma unroll
  for (int i = 0; i < NP; ++i) acc[i] = 0.f;

  for (int f = 0; f < F; ++f) {
    float w = W[(size_t)f * H + h];
#pragma unroll
    for (int i = 0; i < NP; ++i)
      acc[i] += xs[(nl + i * NSLOT) * F + f] * w;
  }

#pragma unroll
  for (int i = 0; i < NP; ++i) {
    int gn = node0 + nl + i * NSLOT;
    if (gn < N) xW[(size_t)gn * H + h] = acc[i];
  }

  // gate + degree scale: 16 groups of 16 lanes, one node per group
  {
    const int g = t >> 4, l = t & 15;
    float as = 0.f, ad = 0.f;
    const float* xr = xs + g * F;
    for (int f = l; f < F; f += 16) {
      float v = xr[f];
      as += v * sc[f];
      ad += v * dkw[f];
    }
#pragma unroll
    for (int off = 8; off; off >>= 1) {
      as += __shfl_down(as, off);
      ad += __shfl_down(ad, off);
    }
    if (l == 0) {
      int gn = node0 + g;
      if (gn < N) {
        s[gn] = 1.f / (1.f + expf(-(as + sb[0])));
        Dk[gn] = ad + dkb[0];
      }
    }
  }
}

// ---------------------------------------------------------------------------
// Kernel B: scatter-add  agg[dst] += w * feat[src]   (one thread per (e,h))
// ---------------------------------------------------------------------------
__global__ __launch_bounds__(256) void scatter_kernel(
    const int* __restrict__ ei, const float* __restrict__ ew,
    const float* __restrict__ feat, float* __restrict__ agg,
    int E, int shift) {
  long long i = (long long)blockIdx.x * blockDim.x + threadIdx.x;
  long long total = (long long)E << shift;
  if (i >= total) return;
  int e = (int)(i >> shift);
  int h = (int)(i & ((1 << shift) - 1));
  int src = ei[e];
  int dst = ei[E + e];
  float v = ew[e] * feat[((size_t)src << shift) + h];
  atomicAdd(&agg[((size_t)dst << shift) + h], v);
}

// ---------------------------------------------------------------------------
// Kernel C: out = s*agg + (1-s)*aggk + GAMMA*Dk*xW
// ---------------------------------------------------------------------------
__global__ __launch_bounds__(256) void combine_kernel(
    const float* __restrict__ s, const float* __restrict__ Dk,
    const float* __restrict__ agg, const float* __restrict__ aggk,
    const float* __restrict__ xW, float* __restrict__ out,
    long long total, int shift) {
  long long i = (long long)blockIdx.x * blockDim.x + threadIdx.x;
  if (i >= total) return;
  int n = (int)(i >> shift);
  float sv = s[n];
  out[i] = sv * agg[i] + (1.f - sv) * aggk[i] + GAMMA * Dk[n] * xW[i];
}

extern "C" void kernel_launch(void* const* d_in, const int* in_sizes, int n_in,
                              void* d_out, int out_size, void* d_ws, size_t ws_size,
                              hipStream_t stream) {
  const float* x = (const float*)d_in[0];
  const int* edge_index = (const int*)d_in[1];
  const float* edge_weight = (const float*)d_in[2];
  const int* knn_edge_index = (const int*)d_in[3];
  const float* knn_edge_weight = (const float*)d_in[4];
  const float* W0 = (const float*)d_in[5];
  const float* W1 = (const float*)d_in[6];
  const float* score0 = (const float*)d_in[7];
  const float* sbias0 = (const float*)d_in[8];
  const float* score1 = (const float*)d_in[9];
  const float* sbias1 = (const float*)d_in[10];
  const float* Dk0 = (const float*)d_in[11];
  const float* Dbias0 = (const float*)d_in[12];
  const float* Dk1 = (const float*)d_in[13];
  const float* Dbias1 = (const float*)d_in[14];

  const int F = in_sizes[7];          // 500
  const int N = in_sizes[0] / F;      // 50000
  const int H = in_sizes[9];          // 64
  const int O = in_sizes[6] / H;      // 16
  const int E = in_sizes[2];          // 1.6M
  const int Ek = in_sizes[4];         // 1.0M
  (void)H; (void)O; (void)n_in; (void)ws_size; (void)out_size;

  // workspace layout (floats)
  float* ws = (float*)d_ws;
  float* xW   = ws;                   // N*64 (reused as N*16 in layer 1)
  float* agg  = xW  + (size_t)N * 64; // N*64
  float* aggk = agg + (size_t)N * 64; // N*64
  float* x1   = aggk + (size_t)N * 64;// N*64
  float* sbuf = x1  + (size_t)N * 64; // N
  float* dkb  = sbuf + N;             // N

  const int nodeBlocks = (N + 15) / 16;

  // ---------------- Layer 0 (F=500 -> H=64) ----------------
  fused_linear<64><<<nodeBlocks, 256, 16 * F * sizeof(float), stream>>>(
      x, W0, score0, sbias0, Dk0, Dbias0, xW, sbuf, dkb, N, F);

  hipMemsetAsync(agg, 0, (size_t)2 * N * 64 * sizeof(float), stream);

  {
    long long tot = (long long)E << 6;
    scatter_kernel<<<(int)((tot + 255) / 256), 256, 0, stream>>>(
        edge_index, edge_weight, xW, agg, E, 6);
    long long totk = (long long)Ek << 6;
    scatter_kernel<<<(int)((totk + 255) / 256), 256, 0, stream>>>(
        knn_edge_index, knn_edge_weight, xW, aggk, Ek, 6);
  }

  {
    long long tot = (long long)N << 6;
    combine_kernel<<<(int)((tot + 255) / 256), 256, 0, stream>>>(
        sbuf, dkb, agg, aggk, xW, x1, tot, 6);
  }

  // ---------------- Layer 1 (F=64 -> O=16) ----------------
  float* aggk1 = agg + (size_t)N * 16;  // pack layer-1 accumulators contiguously
  fused_linear<16><<<nodeBlocks, 256, 16 * 64 * sizeof(float), stream>>>(
      x1, W1, score1, sbias1, Dk1, Dbias1, xW, sbuf, dkb, N, 64);

  hipMemsetAsync(agg, 0, (size_t)2 * N * 16 * sizeof(float), stream);

  {
    long long tot = (long long)E << 4;
    scatter_kernel<<<(int)((tot + 255) / 256), 256, 0, stream>>>(
        edge_index, edge_weight, xW, agg, E, 4);
    long long totk = (long long)Ek << 4;
    scatter_kernel<<<(int)((totk + 255) / 256), 256, 0, stream>>>(
        knn_edge_index, knn_edge_weight, xW, aggk1, Ek, 4);
  }

  {
    long long tot = (long long)N << 4;
    combine_kernel<<<(int)((tot + 255) / 256), 256, 0, stream>>>(
        sbuf, dkb, agg, aggk1, xW, (float*)d_out, tot, 4);
  }
}

// Round 2
// 848.480 us; speedup vs baseline: 1.0251x; 1.0251x over previous
//
#include <hip/hip_runtime.h>
#include <hip/hip_bf16.h>
#include <math.h>

#define GAMMA 0.1f

// ---------------------------------------------------------------------------
// Kernel A: fused  xW = x@W,  s = sigmoid(x@sc+sb),  Dk = x@dkw+dkb
// ---------------------------------------------------------------------------
template <int H>
__global__ __launch_bounds__(256) void fused_linear(
    const float* __restrict__ x, const float* __restrict__ W,
    const float* __restrict__ sc, const float* __restrict__ sb,
    const float* __restrict__ dkw, const float* __restrict__ dkb,
    float* __restrict__ xW, float* __restrict__ s, float* __restrict__ Dk,
    int N, int F) {
  constexpr int BN = 16;                 // nodes per block
  extern __shared__ float xs[];          // [BN][F]
  const int node0 = blockIdx.x * BN;
  const int t = threadIdx.x;

  const int total = BN * F;
  for (int i = t; i < total; i += 256) {
    int n = i / F;
    int f = i - n * F;
    int gn = node0 + n;
    xs[i] = (gn < N) ? x[(size_t)gn * F + f] : 0.f;
  }
  __syncthreads();

  constexpr int NSLOT = 256 / H;
  constexpr int NP = BN / NSLOT;
  const int h = t % H;
  const int nl = t / H;

  float acc[NP];
#pragma unroll
  for (int i = 0; i < NP; ++i) acc[i] = 0.f;

  for (int f = 0; f < F; ++f) {
    float w = W[(size_t)f * H + h];
#pragma unroll
    for (int i = 0; i < NP; ++i)
      acc[i] += xs[(nl + i * NSLOT) * F + f] * w;
  }

#pragma unroll
  for (int i = 0; i < NP; ++i) {
    int gn = node0 + nl + i * NSLOT;
    if (gn < N) xW[(size_t)gn * H + h] = acc[i];
  }

  {
    const int g = t >> 4, l = t & 15;
    float as = 0.f, ad = 0.f;
    const float* xr = xs + g * F;
    for (int f = l; f < F; f += 16) {
      float v = xr[f];
      as += v * sc[f];
      ad += v * dkw[f];
    }
#pragma unroll
    for (int off = 8; off; off >>= 1) {
      as += __shfl_down(as, off);
      ad += __shfl_down(ad, off);
    }
    if (l == 0) {
      int gn = node0 + g;
      if (gn < N) {
        s[gn] = 1.f / (1.f + expf(-(as + sb[0])));
        Dk[gn] = ad + dkb[0];
      }
    }
  }
}

// ---------------------------------------------------------------------------
// CSR build: count -> scan (cursor init) -> fill
// ---------------------------------------------------------------------------
__global__ __launch_bounds__(256) void count_kernel(
    const int* __restrict__ ei, int E, int* __restrict__ cnt) {
  int i = blockIdx.x * 256 + threadIdx.x;
  if (i < E) atomicAdd(&cnt[ei[E + i]], 1);
}

// Single-block scan over N counts. Writes row_ptr[0..N] (exclusive, total at
// end) and rewrites cnt[i] to the exclusive prefix (cursor init for fill).
__global__ __launch_bounds__(1024) void scan_kernel(
    int* __restrict__ cnt, int* __restrict__ row_ptr, int N) {
  __shared__ int part[1024];
  const int t = threadIdx.x;
  const int seg = (N + 1023) >> 10;
  const int lo = t * seg;
  const int hi = min(lo + seg, N);
  int sum = 0;
  for (int i = lo; i < hi; ++i) sum += cnt[i];
  part[t] = sum;
  __syncthreads();
  int v = sum;
  for (int off = 1; off < 1024; off <<= 1) {
    int x = (t >= off) ? part[t - off] : 0;
    __syncthreads();
    v += x;
    part[t] = v;
    __syncthreads();
  }
  int run = (t == 0) ? 0 : part[t - 1];
  for (int i = lo; i < hi; ++i) {
    int c = cnt[i];
    row_ptr[i] = run;
    cnt[i] = run;     // cursor init (aliases counts)
    run += c;
  }
  if (t == 1023) row_ptr[N] = part[1023];
}

__global__ __launch_bounds__(256) void fill_kernel(
    const int* __restrict__ ei, const float* __restrict__ ew, int E,
    int* __restrict__ cursor, int2* __restrict__ rec) {
  int i = blockIdx.x * 256 + threadIdx.x;
  if (i >= E) return;
  int src = ei[i];
  int dst = ei[E + i];
  int pos = atomicAdd(&cursor[dst], 1);
  rec[pos] = make_int2(src, __float_as_int(ew[i]));
}

// ---------------------------------------------------------------------------
// Fused gather-aggregate + combine:
//   out[n] = s[n]*sum_adj(w*feat[src]) + (1-s[n])*sum_knn(w*feat[src])
//            + GAMMA*Dk[n]*feat[n]
// H lanes cooperate per node (lane = feature).
// ---------------------------------------------------------------------------
template <int H>
__global__ __launch_bounds__(256) void agg_combine(
    const int* __restrict__ rpA, const int2* __restrict__ recA,
    const int* __restrict__ rpK, const int2* __restrict__ recK,
    const float* __restrict__ feat, const float* __restrict__ s,
    const float* __restrict__ Dk, float* __restrict__ out, int N) {
  int tid = blockIdx.x * 256 + threadIdx.x;
  int n = tid / H;
  int h = tid % H;
  if (n >= N) return;

  float accA0 = 0.f, accA1 = 0.f, accK0 = 0.f, accK1 = 0.f;
  {
    int b = rpA[n], e = rpA[n + 1];
    int j = b;
    for (; j + 1 < e; j += 2) {
      int2 r0 = recA[j];
      int2 r1 = recA[j + 1];
      accA0 += __int_as_float(r0.y) * feat[(size_t)r0.x * H + h];
      accA1 += __int_as_float(r1.y) * feat[(size_t)r1.x * H + h];
    }
    if (j < e) {
      int2 r0 = recA[j];
      accA0 += __int_as_float(r0.y) * feat[(size_t)r0.x * H + h];
    }
  }
  {
    int b = rpK[n], e = rpK[n + 1];
    int j = b;
    for (; j + 1 < e; j += 2) {
      int2 r0 = recK[j];
      int2 r1 = recK[j + 1];
      accK0 += __int_as_float(r0.y) * feat[(size_t)r0.x * H + h];
      accK1 += __int_as_float(r1.y) * feat[(size_t)r1.x * H + h];
    }
    if (j < e) {
      int2 r0 = recK[j];
      accK0 += __int_as_float(r0.y) * feat[(size_t)r0.x * H + h];
    }
  }
  float sv = s[n];
  float self = feat[(size_t)n * H + h];
  out[(size_t)n * H + h] =
      sv * (accA0 + accA1) + (1.f - sv) * (accK0 + accK1) +
      GAMMA * Dk[n] * self;
}

extern "C" void kernel_launch(void* const* d_in, const int* in_sizes, int n_in,
                              void* d_out, int out_size, void* d_ws, size_t ws_size,
                              hipStream_t stream) {
  const float* x = (const float*)d_in[0];
  const int* edge_index = (const int*)d_in[1];
  const float* edge_weight = (const float*)d_in[2];
  const int* knn_edge_index = (const int*)d_in[3];
  const float* knn_edge_weight = (const float*)d_in[4];
  const float* W0 = (const float*)d_in[5];
  const float* W1 = (const float*)d_in[6];
  const float* score0 = (const float*)d_in[7];
  const float* sbias0 = (const float*)d_in[8];
  const float* score1 = (const float*)d_in[9];
  const float* sbias1 = (const float*)d_in[10];
  const float* Dk0 = (const float*)d_in[11];
  const float* Dbias0 = (const float*)d_in[12];
  const float* Dk1 = (const float*)d_in[13];
  const float* Dbias1 = (const float*)d_in[14];

  const int F = in_sizes[7];          // 500
  const int N = in_sizes[0] / F;      // 50000
  const int E = in_sizes[2];          // 1.6M
  const int Ek = in_sizes[4];         // 1.0M
  (void)n_in; (void)ws_size; (void)out_size;

  // ---- workspace layout ----
  float* ws = (float*)d_ws;
  float* xW  = ws;                          // N*64
  float* x1  = xW + (size_t)N * 64;         // N*64
  int2* recA = (int2*)(x1 + (size_t)N * 64);  // E records (8B each)
  int2* recK = recA + E;                      // Ek records
  float* sbuf = (float*)(recK + Ek);        // N
  float* dkb  = sbuf + N;                   // N
  int* cntA   = (int*)(dkb + N);            // N (counts, then cursors)
  int* cntK   = cntA + N;                   // N
  int* rpA    = cntK + N;                   // N+1
  int* rpK    = rpA + N + 1;                // N+1

  // ---- CSR build (once; reused by both layers) ----
  hipMemsetAsync(cntA, 0, (size_t)2 * N * sizeof(int), stream);
  count_kernel<<<(E + 255) / 256, 256, 0, stream>>>(edge_index, E, cntA);
  count_kernel<<<(Ek + 255) / 256, 256, 0, stream>>>(knn_edge_index, Ek, cntK);
  scan_kernel<<<1, 1024, 0, stream>>>(cntA, rpA, N);
  scan_kernel<<<1, 1024, 0, stream>>>(cntK, rpK, N);
  fill_kernel<<<(E + 255) / 256, 256, 0, stream>>>(edge_index, edge_weight, E,
                                                   cntA, recA);
  fill_kernel<<<(Ek + 255) / 256, 256, 0, stream>>>(knn_edge_index,
                                                    knn_edge_weight, Ek, cntK,
                                                    recK);

  const int nodeBlocks = (N + 15) / 16;

  // ---- Layer 0 (F=500 -> H=64) ----
  fused_linear<64><<<nodeBlocks, 256, 16 * F * sizeof(float), stream>>>(
      x, W0, score0, sbias0, Dk0, Dbias0, xW, sbuf, dkb, N, F);
  agg_combine<64><<<(int)(((size_t)N * 64 + 255) / 256), 256, 0, stream>>>(
      rpA, recA, rpK, recK, xW, sbuf, dkb, x1, N);

  // ---- Layer 1 (F=64 -> O=16) ----
  fused_linear<16><<<nodeBlocks, 256, 16 * 64 * sizeof(float), stream>>>(
      x1, W1, score1, sbias1, Dk1, Dbias1, xW, sbuf, dkb, N, 64);
  agg_combine<16><<<(int)(((size_t)N * 16 + 255) / 256), 256, 0, stream>>>(
      rpA, recA, rpK, recK, xW, sbuf, dkb, (float*)d_out, N);
}

// Round 4
// 541.750 us; speedup vs baseline: 1.6054x; 1.5662x over previous
//
#include <hip/hip_runtime.h>
#include <math.h>

#define GAMMA 0.1f

typedef float f32x4 __attribute__((ext_vector_type(4)));
typedef short short8 __attribute__((ext_vector_type(8)));

static __device__ __forceinline__ unsigned short f2bf(float f) {
  union { float f; unsigned u; } v; v.f = f;
  unsigned r = v.u + 0x7FFF + ((v.u >> 16) & 1);   // RNE
  return (unsigned short)(r >> 16);
}
static __device__ __forceinline__ float bf2f(unsigned short b) {
  union { unsigned u; float f; } v; v.u = ((unsigned)b) << 16;
  return v.f;
}

// ---------------------------------------------------------------------------
// Build transposed bf16 B matrix: Bt[c][k], c in [0,COLS), k in [0,KPAD)
//   c < H : W[k][c];  c == H : sc[k];  c == H+1 : dk[k];  else/k>=Kact : 0
// ---------------------------------------------------------------------------
__global__ __launch_bounds__(256) void build_bt(
    const float* __restrict__ W, const float* __restrict__ sc,
    const float* __restrict__ dk, unsigned short* __restrict__ Bt,
    int H, int Kact, int KPAD, int COLS) {
  int i = blockIdx.x * 256 + threadIdx.x;
  if (i >= COLS * KPAD) return;
  int c = i / KPAD;
  int k = i - c * KPAD;
  float v = 0.f;
  if (k < Kact) {
    if (c < H) v = W[(size_t)k * H + c];
    else if (c == H) v = sc[k];
    else if (c == H + 1) v = dk[k];
  }
  Bt[i] = f2bf(v);
}

// ---------------------------------------------------------------------------
// Fused MFMA linear: out = A @ W (bf16 out), s = sigmoid(A@sc+sb), Dk = A@dk+db
// Block = 256 threads (4 waves), each wave owns 16 rows, all CFRAGS*16 cols.
// mfma_f32_16x16x32_bf16 lane mapping (m89-verified):
//   A: lane l -> A[l&15][kb + (l>>4)*8 + j];  B via Bt[l&15][...]
//   D: lane l, reg r -> D[(l>>4)*4 + r][l&15]
// ---------------------------------------------------------------------------
template <int KPAD, int CFRAGS, int OUTFRAGS, bool ABF>
__global__ __launch_bounds__(256) void mfma_linear(
    const void* __restrict__ Aptr, const unsigned short* __restrict__ Bt,
    const float* __restrict__ sb, const float* __restrict__ db,
    unsigned short* __restrict__ outW, float* __restrict__ s,
    float* __restrict__ Dk, int N, int Kact) {
  constexpr int H = OUTFRAGS * 16;
  const int w = threadIdx.x >> 6;
  const int l = threadIdx.x & 63;
  const int kgrp = l >> 4;          // 0..3
  const int lc = l & 15;
  const int rowA = blockIdx.x * 64 + w * 16 + lc;       // A-fragment row
  const int rowD = blockIdx.x * 64 + w * 16 + kgrp * 4; // D rows base

  f32x4 acc[CFRAGS];
#pragma unroll
  for (int i = 0; i < CFRAGS; ++i) acc[i] = (f32x4)0.f;

  for (int ks = 0; ks < KPAD / 32; ++ks) {
    const int kb = ks * 32 + kgrp * 8;
    short8 av;
    if (rowA < N) {
      if (ABF) {
        av = *(const short8*)((const unsigned short*)Aptr +
                              (size_t)rowA * Kact + kb);
      } else {
        const float* A = (const float*)Aptr + (size_t)rowA * Kact;
        if (kb + 8 <= Kact) {
          f32x4 f0 = *(const f32x4*)(A + kb);
          f32x4 f1 = *(const f32x4*)(A + kb + 4);
#pragma unroll
          for (int j = 0; j < 4; ++j) {
            av[j] = (short)f2bf(f0[j]);
            av[j + 4] = (short)f2bf(f1[j]);
          }
        } else {
#pragma unroll
          for (int j = 0; j < 8; ++j) {
            int f = kb + j;
            av[j] = (short)f2bf(f < Kact ? A[f] : 0.f);
          }
        }
      }
    } else {
#pragma unroll
      for (int j = 0; j < 8; ++j) av[j] = 0;
    }

#pragma unroll
    for (int fc = 0; fc < CFRAGS; ++fc) {
      short8 bv = *(const short8*)(Bt + (size_t)(fc * 16 + lc) * KPAD + kb);
      acc[fc] = __builtin_amdgcn_mfma_f32_16x16x32_bf16(av, bv, acc[fc], 0, 0, 0);
    }
  }

  // epilogue: xW (bf16)
#pragma unroll
  for (int fc = 0; fc < OUTFRAGS; ++fc) {
#pragma unroll
    for (int r = 0; r < 4; ++r) {
      int gr = rowD + r;
      if (gr < N) outW[(size_t)gr * H + fc * 16 + lc] = f2bf(acc[fc][r]);
    }
  }
  // gate + degree columns live in the last fragment (local cols 0 and 1)
  if (lc < 2) {
    f32x4 g = acc[CFRAGS - 1];
#pragma unroll
    for (int r = 0; r < 4; ++r) {
      int gr = rowD + r;
      if (gr < N) {
        if (lc == 0) s[gr] = 1.f / (1.f + expf(-(g[r] + sb[0])));
        else Dk[gr] = g[r] + db[0];
      }
    }
  }
}

// ---------------------------------------------------------------------------
// CSR build: count -> 3-stage parallel scan -> fill
// ---------------------------------------------------------------------------
__global__ __launch_bounds__(256) void count_kernel(
    const int* __restrict__ ei, int E, int* __restrict__ cnt) {
  int i = blockIdx.x * 256 + threadIdx.x;
  if (i < E) atomicAdd(&cnt[ei[E + i]], 1);
}

__global__ __launch_bounds__(256) void scan_partial(
    const int* __restrict__ cnt, int N, int* __restrict__ bsum) {
  __shared__ int sw[4];
  int i = blockIdx.x * 256 + threadIdx.x;
  int v = (i < N) ? cnt[i] : 0;
#pragma unroll
  for (int off = 32; off; off >>= 1) v += __shfl_down(v, off);
  if ((threadIdx.x & 63) == 0) sw[threadIdx.x >> 6] = v;
  __syncthreads();
  if (threadIdx.x == 0) bsum[blockIdx.x] = sw[0] + sw[1] + sw[2] + sw[3];
}

// single block: exclusive-scan bsum[0..nblk), write total to *totalp
__global__ __launch_bounds__(256) void scan_block(
    int* __restrict__ bsum, int nblk, int* __restrict__ totalp) {
  __shared__ int sh[256];
  int t = threadIdx.x;
  int v = (t < nblk) ? bsum[t] : 0;
  sh[t] = v;
  __syncthreads();
  int acc = v;
  for (int off = 1; off < 256; off <<= 1) {
    int x = (t >= off) ? sh[t - off] : 0;
    __syncthreads();
    acc += x;
    sh[t] = acc;
    __syncthreads();
  }
  if (t < nblk) bsum[t] = acc - v;            // exclusive
  if (t == nblk - 1) *totalp = acc;           // grand total -> row_ptr[N]
}

// per block: exclusive scan of its 256 counts + block offset; writes row_ptr
// and rewrites cnt to the exclusive prefix (cursor init for fill)
__global__ __launch_bounds__(256) void scan_final(
    int* __restrict__ cnt, int N, const int* __restrict__ bsum,
    int* __restrict__ row_ptr) {
  __shared__ int sh[256];
  int t = threadIdx.x;
  int i = blockIdx.x * 256 + t;
  int v = (i < N) ? cnt[i] : 0;
  sh[t] = v;
  __syncthreads();
  int acc = v;
  for (int off = 1; off < 256; off <<= 1) {
    int x = (t >= off) ? sh[t - off] : 0;
    __syncthreads();
    acc += x;
    sh[t] = acc;
    __syncthreads();
  }
  if (i < N) {
    int excl = acc - v + bsum[blockIdx.x];
    row_ptr[i] = excl;
    cnt[i] = excl;
  }
}

__global__ __launch_bounds__(256) void fill_kernel(
    const int* __restrict__ ei, const float* __restrict__ ew, int E,
    int* __restrict__ cursor, int2* __restrict__ rec) {
  int i = blockIdx.x * 256 + threadIdx.x;
  if (i >= E) return;
  int src = ei[i];
  int dst = ei[E + i];
  int pos = atomicAdd(&cursor[dst], 1);
  rec[pos] = make_int2(src, __float_as_int(ew[i]));
}

// ---------------------------------------------------------------------------
// Fused gather-aggregate + combine (bf16 feat):
//   out[n] = s[n]*sum_adj(w*feat[src]) + (1-s[n])*sum_knn(w*feat[src])
//            + GAMMA*Dk[n]*feat[n]
// ---------------------------------------------------------------------------
template <int H, bool OUTF32>
__global__ __launch_bounds__(256) void agg_combine(
    const int* __restrict__ rpA, const int2* __restrict__ recA,
    const int* __restrict__ rpK, const int2* __restrict__ recK,
    const unsigned short* __restrict__ feat, const float* __restrict__ s,
    const float* __restrict__ Dk, void* __restrict__ outp, int N) {
  int tid = blockIdx.x * 256 + threadIdx.x;
  int n = tid / H;
  int h = tid % H;
  if (n >= N) return;

  float accA0 = 0.f, accA1 = 0.f, accK0 = 0.f, accK1 = 0.f;
  {
    int b = rpA[n], e = rpA[n + 1];
    int j = b;
    for (; j + 1 < e; j += 2) {
      int2 r0 = recA[j];
      int2 r1 = recA[j + 1];
      accA0 += __int_as_float(r0.y) * bf2f(feat[(size_t)r0.x * H + h]);
      accA1 += __int_as_float(r1.y) * bf2f(feat[(size_t)r1.x * H + h]);
    }
    if (j < e) {
      int2 r0 = recA[j];
      accA0 += __int_as_float(r0.y) * bf2f(feat[(size_t)r0.x * H + h]);
    }
  }
  {
    int b = rpK[n], e = rpK[n + 1];
    int j = b;
    for (; j + 1 < e; j += 2) {
      int2 r0 = recK[j];
      int2 r1 = recK[j + 1];
      accK0 += __int_as_float(r0.y) * bf2f(feat[(size_t)r0.x * H + h]);
      accK1 += __int_as_float(r1.y) * bf2f(feat[(size_t)r1.x * H + h]);
    }
    if (j < e) {
      int2 r0 = recK[j];
      accK0 += __int_as_float(r0.y) * bf2f(feat[(size_t)r0.x * H + h]);
    }
  }
  float sv = s[n];
  float self = bf2f(feat[(size_t)n * H + h]);
  float res = sv * (accA0 + accA1) + (1.f - sv) * (accK0 + accK1) +
              GAMMA * Dk[n] * self;
  if (OUTF32) ((float*)outp)[(size_t)n * H + h] = res;
  else ((unsigned short*)outp)[(size_t)n * H + h] = f2bf(res);
}

// ---------------------------------------------------------------------------
extern "C" void kernel_launch(void* const* d_in, const int* in_sizes, int n_in,
                              void* d_out, int out_size, void* d_ws, size_t ws_size,
                              hipStream_t stream) {
  const float* x = (const float*)d_in[0];
  const int* edge_index = (const int*)d_in[1];
  const float* edge_weight = (const float*)d_in[2];
  const int* knn_edge_index = (const int*)d_in[3];
  const float* knn_edge_weight = (const float*)d_in[4];
  const float* W0 = (const float*)d_in[5];
  const float* W1 = (const float*)d_in[6];
  const float* score0 = (const float*)d_in[7];
  const float* sbias0 = (const float*)d_in[8];
  const float* score1 = (const float*)d_in[9];
  const float* sbias1 = (const float*)d_in[10];
  const float* Dk0 = (const float*)d_in[11];
  const float* Dbias0 = (const float*)d_in[12];
  const float* Dk1 = (const float*)d_in[13];
  const float* Dbias1 = (const float*)d_in[14];

  const int F = in_sizes[7];          // 500
  const int N = in_sizes[0] / F;      // 50000
  const int E = in_sizes[2];          // 1.6M
  const int Ek = in_sizes[4];         // 1.0M
  (void)n_in; (void)ws_size; (void)out_size;

  // ---- workspace bump allocator (256B-aligned slices) ----
  char* cur = (char*)d_ws;
  auto alloc = [&](size_t bytes) {
    char* p = cur;
    cur += (bytes + 255) & ~(size_t)255;
    return (void*)p;
  };
  float* sbuf = (float*)alloc((size_t)N * 4);
  float* dkbuf = (float*)alloc((size_t)N * 4);
  // counts MUST be one contiguous slice: a single memset zeroes both exactly.
  // (R2 bug: separate 256B-padded slices left a 48-int unzeroed gap in cntK
  //  -> garbage cursors -> OOB rec[] writes -> GPU fault.)
  int* cnt2 = (int*)alloc((size_t)2 * N * 4);
  int* cntA = cnt2;
  int* cntK = cnt2 + N;
  int* rpA = (int*)alloc((size_t)(N + 1) * 4);
  int* rpK = (int*)alloc((size_t)(N + 1) * 4);
  int* bsA = (int*)alloc(256 * 4);
  int* bsK = (int*)alloc(256 * 4);
  int2* recA = (int2*)alloc((size_t)E * 8);
  int2* recK = (int2*)alloc((size_t)Ek * 8);
  unsigned short* Bt0 = (unsigned short*)alloc((size_t)80 * 512 * 2);
  unsigned short* Bt1 = (unsigned short*)alloc((size_t)32 * 64 * 2);
  unsigned short* xWb = (unsigned short*)alloc((size_t)N * 64 * 2);
  unsigned short* x1b = (unsigned short*)alloc((size_t)N * 64 * 2);
  unsigned short* xW1b = (unsigned short*)alloc((size_t)N * 16 * 2);

  const int nscan = (N + 255) / 256;  // 196

  // ---- B transposes (tiny) ----
  build_bt<<<(80 * 512 + 255) / 256, 256, 0, stream>>>(W0, score0, Dk0, Bt0,
                                                       64, F, 512, 80);
  build_bt<<<(32 * 64 + 255) / 256, 256, 0, stream>>>(W1, score1, Dk1, Bt1,
                                                      16, 64, 64, 32);

  // ---- CSR build (reused by both layers) ----
  hipMemsetAsync(cnt2, 0, (size_t)2 * N * sizeof(int), stream);
  count_kernel<<<(E + 255) / 256, 256, 0, stream>>>(edge_index, E, cntA);
  count_kernel<<<(Ek + 255) / 256, 256, 0, stream>>>(knn_edge_index, Ek, cntK);
  scan_partial<<<nscan, 256, 0, stream>>>(cntA, N, bsA);
  scan_partial<<<nscan, 256, 0, stream>>>(cntK, N, bsK);
  scan_block<<<1, 256, 0, stream>>>(bsA, nscan, rpA + N);
  scan_block<<<1, 256, 0, stream>>>(bsK, nscan, rpK + N);
  scan_final<<<nscan, 256, 0, stream>>>(cntA, N, bsA, rpA);
  scan_final<<<nscan, 256, 0, stream>>>(cntK, N, bsK, rpK);
  fill_kernel<<<(E + 255) / 256, 256, 0, stream>>>(edge_index, edge_weight, E,
                                                   cntA, recA);
  fill_kernel<<<(Ek + 255) / 256, 256, 0, stream>>>(knn_edge_index,
                                                    knn_edge_weight, Ek, cntK,
                                                    recK);

  const int gemmBlocks = (N + 63) / 64;

  // ---- Layer 0: F=500 -> H=64 (+gate+Dk) ----
  mfma_linear<512, 5, 4, false><<<gemmBlocks, 256, 0, stream>>>(
      x, Bt0, sbias0, Dbias0, xWb, sbuf, dkbuf, N, F);
  agg_combine<64, false><<<(int)(((size_t)N * 64 + 255) / 256), 256, 0, stream>>>(
      rpA, recA, rpK, recK, xWb, sbuf, dkbuf, x1b, N);

  // ---- Layer 1: H=64 -> O=16 (+gate+Dk) ----
  mfma_linear<64, 2, 1, true><<<gemmBlocks, 256, 0, stream>>>(
      x1b, Bt1, sbias1, Dbias1, xW1b, sbuf, dkbuf, N, 64);
  agg_combine<16, true><<<(int)(((size_t)N * 16 + 255) / 256), 256, 0, stream>>>(
      rpA, recA, rpK, recK, xW1b, sbuf, dkbuf, d_out, N);
}

// Round 5
// 488.235 us; speedup vs baseline: 1.7814x; 1.1096x over previous
//
#include <hip/hip_runtime.h>
#include <math.h>

#define GAMMA 0.1f

typedef float f32x4 __attribute__((ext_vector_type(4)));
typedef short short8 __attribute__((ext_vector_type(8)));

static __device__ __forceinline__ unsigned short f2bf(float f) {
  union { float f; unsigned u; } v; v.f = f;
  unsigned r = v.u + 0x7FFF + ((v.u >> 16) & 1);   // RNE
  return (unsigned short)(r >> 16);
}
static __device__ __forceinline__ float bf2f(unsigned short b) {
  union { unsigned u; float f; } v; v.u = ((unsigned)b) << 16;
  return v.f;
}

// ---------------------------------------------------------------------------
// Build transposed bf16 B matrix: Bt[c][k], c in [0,COLS), k in [0,KPAD)
//   c < H : W[k][c];  c == H : sc[k];  c == H+1 : dk[k];  else/k>=Kact : 0
// ---------------------------------------------------------------------------
__global__ __launch_bounds__(256) void build_bt(
    const float* __restrict__ W, const float* __restrict__ sc,
    const float* __restrict__ dk, unsigned short* __restrict__ Bt,
    int H, int Kact, int KPAD, int COLS) {
  int i = blockIdx.x * 256 + threadIdx.x;
  if (i >= COLS * KPAD) return;
  int c = i / KPAD;
  int k = i - c * KPAD;
  float v = 0.f;
  if (k < Kact) {
    if (c < H) v = W[(size_t)k * H + c];
    else if (c == H) v = sc[k];
    else if (c == H + 1) v = dk[k];
  }
  Bt[i] = f2bf(v);
}

// ---------------------------------------------------------------------------
// Fused MFMA linear: out = A @ W (bf16 out), s = sigmoid(A@sc+sb), Dk = A@dk+db
// Block = 256 threads (4 waves), each wave owns 16 rows, all CFRAGS*16 cols.
// mfma_f32_16x16x32_bf16 lane mapping (m89-verified):
//   A: lane l -> A[l&15][kb + (l>>4)*8 + j];  B via Bt[l&15][...]
//   D: lane l, reg r -> D[(l>>4)*4 + r][l&15]
// ---------------------------------------------------------------------------
template <int KPAD, int CFRAGS, int OUTFRAGS, bool ABF>
__global__ __launch_bounds__(256) void mfma_linear(
    const void* __restrict__ Aptr, const unsigned short* __restrict__ Bt,
    const float* __restrict__ sb, const float* __restrict__ db,
    unsigned short* __restrict__ outW, float* __restrict__ s,
    float* __restrict__ Dk, int N, int Kact) {
  constexpr int H = OUTFRAGS * 16;
  const int w = threadIdx.x >> 6;
  const int l = threadIdx.x & 63;
  const int kgrp = l >> 4;          // 0..3
  const int lc = l & 15;
  const int rowA = blockIdx.x * 64 + w * 16 + lc;       // A-fragment row
  const int rowD = blockIdx.x * 64 + w * 16 + kgrp * 4; // D rows base

  f32x4 acc[CFRAGS];
#pragma unroll
  for (int i = 0; i < CFRAGS; ++i) acc[i] = (f32x4)0.f;

  for (int ks = 0; ks < KPAD / 32; ++ks) {
    const int kb = ks * 32 + kgrp * 8;
    short8 av;
    if (rowA < N) {
      if (ABF) {
        av = *(const short8*)((const unsigned short*)Aptr +
                              (size_t)rowA * Kact + kb);
      } else {
        const float* A = (const float*)Aptr + (size_t)rowA * Kact;
        if (kb + 8 <= Kact) {
          f32x4 f0 = *(const f32x4*)(A + kb);
          f32x4 f1 = *(const f32x4*)(A + kb + 4);
#pragma unroll
          for (int j = 0; j < 4; ++j) {
            av[j] = (short)f2bf(f0[j]);
            av[j + 4] = (short)f2bf(f1[j]);
          }
        } else {
#pragma unroll
          for (int j = 0; j < 8; ++j) {
            int f = kb + j;
            av[j] = (short)f2bf(f < Kact ? A[f] : 0.f);
          }
        }
      }
    } else {
#pragma unroll
      for (int j = 0; j < 8; ++j) av[j] = 0;
    }

#pragma unroll
    for (int fc = 0; fc < CFRAGS; ++fc) {
      short8 bv = *(const short8*)(Bt + (size_t)(fc * 16 + lc) * KPAD + kb);
      acc[fc] = __builtin_amdgcn_mfma_f32_16x16x32_bf16(av, bv, acc[fc], 0, 0, 0);
    }
  }

  // epilogue: xW (bf16)
#pragma unroll
  for (int fc = 0; fc < OUTFRAGS; ++fc) {
#pragma unroll
    for (int r = 0; r < 4; ++r) {
      int gr = rowD + r;
      if (gr < N) outW[(size_t)gr * H + fc * 16 + lc] = f2bf(acc[fc][r]);
    }
  }
  // gate + degree columns live in the last fragment (local cols 0 and 1)
  if (lc < 2) {
    f32x4 g = acc[CFRAGS - 1];
#pragma unroll
    for (int r = 0; r < 4; ++r) {
      int gr = rowD + r;
      if (gr < N) {
        if (lc == 0) s[gr] = 1.f / (1.f + expf(-(g[r] + sb[0])));
        else Dk[gr] = g[r] + db[0];
      }
    }
  }
}

// ---------------------------------------------------------------------------
// CSR build: count -> 3-stage parallel scan -> fill
// ---------------------------------------------------------------------------
__global__ __launch_bounds__(256) void count_kernel(
    const int* __restrict__ ei, int E, int* __restrict__ cnt) {
  int i = blockIdx.x * 256 + threadIdx.x;
  if (i < E) atomicAdd(&cnt[ei[E + i]], 1);
}

__global__ __launch_bounds__(256) void scan_partial(
    const int* __restrict__ cnt, int N, int* __restrict__ bsum) {
  __shared__ int sw[4];
  int i = blockIdx.x * 256 + threadIdx.x;
  int v = (i < N) ? cnt[i] : 0;
#pragma unroll
  for (int off = 32; off; off >>= 1) v += __shfl_down(v, off);
  if ((threadIdx.x & 63) == 0) sw[threadIdx.x >> 6] = v;
  __syncthreads();
  if (threadIdx.x == 0) bsum[blockIdx.x] = sw[0] + sw[1] + sw[2] + sw[3];
}

// single block: exclusive-scan bsum[0..nblk), write total to *totalp
__global__ __launch_bounds__(256) void scan_block(
    int* __restrict__ bsum, int nblk, int* __restrict__ totalp) {
  __shared__ int sh[256];
  int t = threadIdx.x;
  int v = (t < nblk) ? bsum[t] : 0;
  sh[t] = v;
  __syncthreads();
  int acc = v;
  for (int off = 1; off < 256; off <<= 1) {
    int x = (t >= off) ? sh[t - off] : 0;
    __syncthreads();
    acc += x;
    sh[t] = acc;
    __syncthreads();
  }
  if (t < nblk) bsum[t] = acc - v;            // exclusive
  if (t == nblk - 1) *totalp = acc;           // grand total -> row_ptr[N]
}

// per block: exclusive scan of its 256 counts + block offset; writes row_ptr
// and rewrites cnt to the exclusive prefix (cursor init for fill)
__global__ __launch_bounds__(256) void scan_final(
    int* __restrict__ cnt, int N, const int* __restrict__ bsum,
    int* __restrict__ row_ptr) {
  __shared__ int sh[256];
  int t = threadIdx.x;
  int i = blockIdx.x * 256 + t;
  int v = (i < N) ? cnt[i] : 0;
  sh[t] = v;
  __syncthreads();
  int acc = v;
  for (int off = 1; off < 256; off <<= 1) {
    int x = (t >= off) ? sh[t - off] : 0;
    __syncthreads();
    acc += x;
    sh[t] = acc;
    __syncthreads();
  }
  if (i < N) {
    int excl = acc - v + bsum[blockIdx.x];
    row_ptr[i] = excl;
    cnt[i] = excl;
  }
}

__global__ __launch_bounds__(256) void fill_kernel(
    const int* __restrict__ ei, const float* __restrict__ ew, int E,
    int* __restrict__ cursor, int2* __restrict__ rec) {
  int i = blockIdx.x * 256 + threadIdx.x;
  if (i >= E) return;
  int src = ei[i];
  int dst = ei[E + i];
  int pos = atomicAdd(&cursor[dst], 1);
  rec[pos] = make_int2(src, __float_as_int(ew[i]));
}

// ---------------------------------------------------------------------------
// Gather-sum over one CSR row with 8 independent chains (MLP boost).
// ---------------------------------------------------------------------------
template <int H>
static __device__ __forceinline__ float gather_sum(
    const int* __restrict__ rp, const int2* __restrict__ rec,
    const unsigned short* __restrict__ feat, int n, int h) {
  int b = rp[n], e = rp[n + 1];
  float a0 = 0.f, a1 = 0.f, a2 = 0.f, a3 = 0.f;
  float a4 = 0.f, a5 = 0.f, a6 = 0.f, a7 = 0.f;
  int j = b;
  for (; j + 8 <= e; j += 8) {
    int2 r0 = rec[j + 0];
    int2 r1 = rec[j + 1];
    int2 r2 = rec[j + 2];
    int2 r3 = rec[j + 3];
    int2 r4 = rec[j + 4];
    int2 r5 = rec[j + 5];
    int2 r6 = rec[j + 6];
    int2 r7 = rec[j + 7];
    a0 += __int_as_float(r0.y) * bf2f(feat[(size_t)r0.x * H + h]);
    a1 += __int_as_float(r1.y) * bf2f(feat[(size_t)r1.x * H + h]);
    a2 += __int_as_float(r2.y) * bf2f(feat[(size_t)r2.x * H + h]);
    a3 += __int_as_float(r3.y) * bf2f(feat[(size_t)r3.x * H + h]);
    a4 += __int_as_float(r4.y) * bf2f(feat[(size_t)r4.x * H + h]);
    a5 += __int_as_float(r5.y) * bf2f(feat[(size_t)r5.x * H + h]);
    a6 += __int_as_float(r6.y) * bf2f(feat[(size_t)r6.x * H + h]);
    a7 += __int_as_float(r7.y) * bf2f(feat[(size_t)r7.x * H + h]);
  }
  for (; j < e; ++j) {
    int2 r = rec[j];
    a0 += __int_as_float(r.y) * bf2f(feat[(size_t)r.x * H + h]);
  }
  return ((a0 + a1) + (a2 + a3)) + ((a4 + a5) + (a6 + a7));
}

// ---------------------------------------------------------------------------
// Fused gather-aggregate + combine (bf16 feat):
//   out[n] = s[n]*sum_adj(w*feat[src]) + (1-s[n])*sum_knn(w*feat[src])
//            + GAMMA*Dk[n]*feat[n]
// ---------------------------------------------------------------------------
template <int H, bool OUTF32>
__global__ __launch_bounds__(256) void agg_combine(
    const int* __restrict__ rpA, const int2* __restrict__ recA,
    const int* __restrict__ rpK, const int2* __restrict__ recK,
    const unsigned short* __restrict__ feat, const float* __restrict__ s,
    const float* __restrict__ Dk, void* __restrict__ outp, int N) {
  int tid = blockIdx.x * 256 + threadIdx.x;
  int n = tid / H;
  int h = tid % H;
  if (n >= N) return;

  float aA = gather_sum<H>(rpA, recA, feat, n, h);
  float aK = gather_sum<H>(rpK, recK, feat, n, h);

  float sv = s[n];
  float self = bf2f(feat[(size_t)n * H + h]);
  float res = sv * aA + (1.f - sv) * aK + GAMMA * Dk[n] * self;
  if (OUTF32) ((float*)outp)[(size_t)n * H + h] = res;
  else ((unsigned short*)outp)[(size_t)n * H + h] = f2bf(res);
}

// ---------------------------------------------------------------------------
extern "C" void kernel_launch(void* const* d_in, const int* in_sizes, int n_in,
                              void* d_out, int out_size, void* d_ws, size_t ws_size,
                              hipStream_t stream) {
  const float* x = (const float*)d_in[0];
  const int* edge_index = (const int*)d_in[1];
  const float* edge_weight = (const float*)d_in[2];
  const int* knn_edge_index = (const int*)d_in[3];
  const float* knn_edge_weight = (const float*)d_in[4];
  const float* W0 = (const float*)d_in[5];
  const float* W1 = (const float*)d_in[6];
  const float* score0 = (const float*)d_in[7];
  const float* sbias0 = (const float*)d_in[8];
  const float* score1 = (const float*)d_in[9];
  const float* sbias1 = (const float*)d_in[10];
  const float* Dk0 = (const float*)d_in[11];
  const float* Dbias0 = (const float*)d_in[12];
  const float* Dk1 = (const float*)d_in[13];
  const float* Dbias1 = (const float*)d_in[14];

  const int F = in_sizes[7];          // 500
  const int N = in_sizes[0] / F;      // 50000
  const int E = in_sizes[2];          // 1.6M
  const int Ek = in_sizes[4];         // 1.0M
  (void)n_in; (void)ws_size; (void)out_size;

  // ---- workspace bump allocator (256B-aligned slices) ----
  char* cur = (char*)d_ws;
  auto alloc = [&](size_t bytes) {
    char* p = cur;
    cur += (bytes + 255) & ~(size_t)255;
    return (void*)p;
  };
  float* sbuf = (float*)alloc((size_t)N * 4);
  float* dkbuf = (float*)alloc((size_t)N * 4);
  // counts as ONE contiguous slice so a single memset zeroes both exactly
  // (R2 bug: padded slices left an unzeroed gap -> OOB writes -> fault).
  int* cnt2 = (int*)alloc((size_t)2 * N * 4);
  int* cntA = cnt2;
  int* cntK = cnt2 + N;
  int* rpA = (int*)alloc((size_t)(N + 1) * 4);
  int* rpK = (int*)alloc((size_t)(N + 1) * 4);
  int* bsA = (int*)alloc(256 * 4);
  int* bsK = (int*)alloc(256 * 4);
  int2* recA = (int2*)alloc((size_t)E * 8);
  int2* recK = (int2*)alloc((size_t)Ek * 8);
  unsigned short* Bt0 = (unsigned short*)alloc((size_t)80 * 512 * 2);
  unsigned short* Bt1 = (unsigned short*)alloc((size_t)32 * 64 * 2);
  unsigned short* xWb = (unsigned short*)alloc((size_t)N * 64 * 2);
  unsigned short* x1b = (unsigned short*)alloc((size_t)N * 64 * 2);
  unsigned short* xW1b = (unsigned short*)alloc((size_t)N * 16 * 2);

  const int nscan = (N + 255) / 256;  // 196

  // ---- B transposes (tiny) ----
  build_bt<<<(80 * 512 + 255) / 256, 256, 0, stream>>>(W0, score0, Dk0, Bt0,
                                                       64, F, 512, 80);
  build_bt<<<(32 * 64 + 255) / 256, 256, 0, stream>>>(W1, score1, Dk1, Bt1,
                                                      16, 64, 64, 32);

  // ---- CSR build (reused by both layers) ----
  hipMemsetAsync(cnt2, 0, (size_t)2 * N * sizeof(int), stream);
  count_kernel<<<(E + 255) / 256, 256, 0, stream>>>(edge_index, E, cntA);
  count_kernel<<<(Ek + 255) / 256, 256, 0, stream>>>(knn_edge_index, Ek, cntK);
  scan_partial<<<nscan, 256, 0, stream>>>(cntA, N, bsA);
  scan_partial<<<nscan, 256, 0, stream>>>(cntK, N, bsK);
  scan_block<<<1, 256, 0, stream>>>(bsA, nscan, rpA + N);
  scan_block<<<1, 256, 0, stream>>>(bsK, nscan, rpK + N);
  scan_final<<<nscan, 256, 0, stream>>>(cntA, N, bsA, rpA);
  scan_final<<<nscan, 256, 0, stream>>>(cntK, N, bsK, rpK);
  fill_kernel<<<(E + 255) / 256, 256, 0, stream>>>(edge_index, edge_weight, E,
                                                   cntA, recA);
  fill_kernel<<<(Ek + 255) / 256, 256, 0, stream>>>(knn_edge_index,
                                                    knn_edge_weight, Ek, cntK,
                                                    recK);

  const int gemmBlocks = (N + 63) / 64;

  // ---- Layer 0: F=500 -> H=64 (+gate+Dk) ----
  mfma_linear<512, 5, 4, false><<<gemmBlocks, 256, 0, stream>>>(
      x, Bt0, sbias0, Dbias0, xWb, sbuf, dkbuf, N, F);
  agg_combine<64, false><<<(int)(((size_t)N * 64 + 255) / 256), 256, 0, stream>>>(
      rpA, recA, rpK, recK, xWb, sbuf, dkbuf, x1b, N);

  // ---- Layer 1: H=64 -> O=16 (+gate+Dk) ----
  mfma_linear<64, 2, 1, true><<<gemmBlocks, 256, 0, stream>>>(
      x1b, Bt1, sbias1, Dbias1, xW1b, sbuf, dkbuf, N, 64);
  agg_combine<16, true><<<(int)(((size_t)N * 16 + 255) / 256), 256, 0, stream>>>(
      rpA, recA, rpK, recK, xW1b, sbuf, dkbuf, d_out, N);
}